// Round 1
// baseline (1800.521 us; speedup 1.0000x reference)
//
#include <hip/hip_runtime.h>

#define IN_CH 128
#define OUT_CH 10

// ---------------------------------------------------------------------------
// k_init: deg[i] = 1.0 (self-loop contribution). Re-run every launch since
// the harness does not re-poison/zero d_ws between replays.
// ---------------------------------------------------------------------------
__global__ void k_init(float* __restrict__ deg, int n) {
    int i = blockIdx.x * blockDim.x + threadIdx.x;
    int stride = gridDim.x * blockDim.x;
    for (; i < n; i += stride) deg[i] = 1.0f;
}

// ---------------------------------------------------------------------------
// k_detect: decide whether edge_index arrived as int64 or int32.
// For int64 (values < 2^17), every odd 32-bit word (the high half) is zero.
// For int32 random indices in [0,100000), the odd words are ~never all zero.
// flag = 1 -> int32 data, flag = 0 -> int64 data. Deterministic (data-fixed).
// ---------------------------------------------------------------------------
__global__ void k_detect(const unsigned int* __restrict__ w, int* flag,
                         int nwords_check) {
    __shared__ int any_nz;
    if (threadIdx.x == 0) any_nz = 0;
    __syncthreads();
    int local = 0;
    for (int i = threadIdx.x; i < nwords_check; i += blockDim.x)
        if (w[2 * i + 1] != 0u) local = 1;
    if (local) atomicOr(&any_nz, 1);
    __syncthreads();
    if (threadIdx.x == 0) *flag = any_nz;
}

// ---------------------------------------------------------------------------
// k_deg: deg[dst] += 1 for every edge. Reads only the dst half of edge_index.
// ---------------------------------------------------------------------------
__global__ void k_deg(const void* __restrict__ ei, float* __restrict__ deg,
                      const int* __restrict__ flag, int E) {
    const bool is32 = (*flag != 0);
    long long i = (long long)blockIdx.x * blockDim.x + threadIdx.x;
    long long stride = (long long)gridDim.x * blockDim.x;
    if (is32) {
        const int* dst = (const int*)ei + E;
        for (; i < E; i += stride) atomicAdd(&deg[dst[i]], 1.0f);
    } else {
        const long long* dst = (const long long*)ei + E;
        for (; i < E; i += stride) atomicAdd(&deg[(int)dst[i]], 1.0f);
    }
}

// ---------------------------------------------------------------------------
// k_xw: per node n: dinv[n] = rsqrt(deg[n]); y[n] = dinv[n] * (x[n] @ W);
// seed out[n] = y[n] (the self-loop message, norm = dinv[n]^2 folded into the
// final dinv[d] scale). W staged transposed in LDS; x read as float4.
// ---------------------------------------------------------------------------
__global__ void k_xw(const float* __restrict__ x, const float* __restrict__ W,
                     const float* __restrict__ deg, float* __restrict__ dinv,
                     float* __restrict__ y, float* __restrict__ out, int N) {
    __shared__ float Wt[OUT_CH][IN_CH];  // 5 KB, transposed for float4 reads
    for (int i = threadIdx.x; i < IN_CH * OUT_CH; i += blockDim.x) {
        int k = i / OUT_CH, c = i - k * OUT_CH;
        Wt[c][k] = W[i];
    }
    __syncthreads();

    int n = blockIdx.x * blockDim.x + threadIdx.x;
    if (n >= N) return;

    float acc[OUT_CH];
#pragma unroll
    for (int c = 0; c < OUT_CH; ++c) acc[c] = 0.0f;

    const float4* xr = (const float4*)(x + (size_t)n * IN_CH);
#pragma unroll 4
    for (int k4 = 0; k4 < IN_CH / 4; ++k4) {
        float4 xv = xr[k4];
#pragma unroll
        for (int c = 0; c < OUT_CH; ++c) {
            float4 wv = *(const float4*)&Wt[c][k4 * 4];  // wave-uniform bcast
            acc[c] += xv.x * wv.x + xv.y * wv.y + xv.z * wv.z + xv.w * wv.w;
        }
    }

    float d = rsqrtf(deg[n]);
    dinv[n] = d;
    float2* yr = (float2*)(y + (size_t)n * OUT_CH);     // n*40 B: 8-aligned
    float2* orow = (float2*)(out + (size_t)n * OUT_CH);
#pragma unroll
    for (int c2 = 0; c2 < OUT_CH / 2; ++c2) {
        float2 v;
        v.x = d * acc[2 * c2];
        v.y = d * acc[2 * c2 + 1];
        yr[c2] = v;
        orow[c2] = v;  // self-loop seed
    }
}

// ---------------------------------------------------------------------------
// k_scatter: for each edge (s,t): out[t][:] += y[s][:]  (10 f32 atomics)
// ---------------------------------------------------------------------------
__global__ void k_scatter(const void* __restrict__ ei,
                          const float* __restrict__ y, float* __restrict__ out,
                          const int* __restrict__ flag, int E) {
    const bool is32 = (*flag != 0);
    long long i = (long long)blockIdx.x * blockDim.x + threadIdx.x;
    long long stride = (long long)gridDim.x * blockDim.x;
    for (; i < E; i += stride) {
        long long s, t;
        if (is32) {
            const int* ei32 = (const int*)ei;
            s = ei32[i];
            t = ei32[E + i];
        } else {
            const long long* ei64 = (const long long*)ei;
            s = ei64[i];
            t = ei64[E + i];
        }
        const float2* yr = (const float2*)(y + s * OUT_CH);
        float2 v0 = yr[0], v1 = yr[1], v2 = yr[2], v3 = yr[3], v4 = yr[4];
        float* orow = out + t * OUT_CH;
        atomicAdd(&orow[0], v0.x);
        atomicAdd(&orow[1], v0.y);
        atomicAdd(&orow[2], v1.x);
        atomicAdd(&orow[3], v1.y);
        atomicAdd(&orow[4], v2.x);
        atomicAdd(&orow[5], v2.y);
        atomicAdd(&orow[6], v3.x);
        atomicAdd(&orow[7], v3.y);
        atomicAdd(&orow[8], v4.x);
        atomicAdd(&orow[9], v4.y);
    }
}

// ---------------------------------------------------------------------------
// k_final: out[n][c] = dinv[n] * out[n][c] + b[c]   (in place)
// ---------------------------------------------------------------------------
__global__ void k_final(const float* __restrict__ dinv,
                        const float* __restrict__ b, float* __restrict__ out,
                        int N) {
    int n = blockIdx.x * blockDim.x + threadIdx.x;
    if (n >= N) return;
    float d = dinv[n];
    float2* orow = (float2*)(out + (size_t)n * OUT_CH);
#pragma unroll
    for (int c2 = 0; c2 < OUT_CH / 2; ++c2) {
        float2 v = orow[c2];
        v.x = v.x * d + b[2 * c2];
        v.y = v.y * d + b[2 * c2 + 1];
        orow[c2] = v;
    }
}

extern "C" void kernel_launch(void* const* d_in, const int* in_sizes, int n_in,
                              void* d_out, int out_size, void* d_ws,
                              size_t ws_size, hipStream_t stream) {
    const float* x = (const float*)d_in[0];
    const void* ei = d_in[1];
    const float* W = (const float*)d_in[2];
    const float* b = (const float*)d_in[3];
    float* out = (float*)d_out;

    int N = in_sizes[0] / IN_CH;   // 100000
    int E = in_sizes[1] / 2;       // 3200000 (element count, dtype-agnostic)

    // ws layout (floats): deg[N] | dinv[N] | y[N*OUT_CH] | flag(int)
    float* ws = (float*)d_ws;
    float* deg = ws;
    float* dinv = ws + N;
    float* y = ws + 2 * (size_t)N;
    int* flag = (int*)(ws + 2 * (size_t)N + (size_t)N * OUT_CH);

    int nblk = (N + 255) / 256;
    k_init<<<nblk, 256, 0, stream>>>(deg, N);
    k_detect<<<1, 256, 0, stream>>>((const unsigned int*)ei, flag, 8192);
    k_deg<<<4096, 256, 0, stream>>>(ei, deg, flag, E);
    k_xw<<<nblk, 256, 0, stream>>>(x, W, deg, dinv, y, out, N);
    k_scatter<<<4096, 256, 0, stream>>>(ei, y, out, flag, E);
    k_final<<<nblk, 256, 0, stream>>>(dinv, b, out, N);
}

// Round 2
// 499.872 us; speedup vs baseline: 3.6020x; 3.6020x over previous
//
#include <hip/hip_runtime.h>

#define IN_CH 128
#define OUT_CH 10

// ============================================================================
// Shared helpers
// ============================================================================

// Detect whether edge_index arrived as int64 or int32.
// For int64 (values < 2^17) every odd 32-bit word (high half) is zero.
// flag = 1 -> int32 data, flag = 0 -> int64 data. Deterministic.
__global__ void k_detect(const unsigned int* __restrict__ w, int* flag,
                         int nwords_check) {
    __shared__ int any_nz;
    if (threadIdx.x == 0) any_nz = 0;
    __syncthreads();
    int local = 0;
    for (int i = threadIdx.x; i < nwords_check; i += blockDim.x)
        if (w[2 * i + 1] != 0u) local = 1;
    if (local) atomicOr(&any_nz, 1);
    __syncthreads();
    if (threadIdx.x == 0) *flag = any_nz;
}

// ============================================================================
// CSR-gather path (primary)
// ============================================================================

__global__ void k_zero_i(int* __restrict__ p, int n) {
    int i = blockIdx.x * blockDim.x + threadIdx.x;
    int stride = gridDim.x * blockDim.x;
    for (; i < n; i += stride) p[i] = 0;
}

// cnt[dst]++ per edge (int atomics)
__global__ void k_count(const void* __restrict__ ei, int* __restrict__ cnt,
                        const int* __restrict__ flag, int E) {
    const bool is32 = (*flag != 0);
    long long i = (long long)blockIdx.x * blockDim.x + threadIdx.x;
    long long stride = (long long)gridDim.x * blockDim.x;
    if (is32) {
        const int* dst = (const int*)ei + E;
        for (; i < E; i += stride) atomicAdd(&cnt[dst[i]], 1);
    } else {
        const long long* dst = (const long long*)ei + E;
        for (; i < E; i += stride) atomicAdd(&cnt[(int)dst[i]], 1);
    }
}

// Per-block sums of cnt (256 elements per block)
__global__ void k_scan_block(const int* __restrict__ cnt,
                             int* __restrict__ blocksum, int N) {
    __shared__ int s[256];
    int tid = threadIdx.x;
    int i = blockIdx.x * 256 + tid;
    s[tid] = (i < N) ? cnt[i] : 0;
    __syncthreads();
    for (int off = 128; off; off >>= 1) {
        if (tid < off) s[tid] += s[tid + off];
        __syncthreads();
    }
    if (tid == 0) blocksum[blockIdx.x] = s[0];
}

// Exclusive scan of blocksum[nb] in one block (nb <= 512)
__global__ void k_scan_top(int* __restrict__ blocksum, int nb) {
    __shared__ int s[512];
    int tid = threadIdx.x;
    int v = (tid < nb) ? blocksum[tid] : 0;
    s[tid] = v;
    __syncthreads();
    for (int off = 1; off < 512; off <<= 1) {
        int t = (tid >= off) ? s[tid - off] : 0;
        __syncthreads();
        s[tid] += t;
        __syncthreads();
    }
    if (tid < nb) blocksum[tid] = s[tid] - v;  // exclusive = inclusive - self
}

// rowptr[i] = cursor[i] = block-exclusive-scan(cnt) + blocksum[blockIdx]
__global__ void k_scan_apply(const int* __restrict__ cnt,
                             const int* __restrict__ blocksum,
                             int* __restrict__ rowptr, int* __restrict__ cursor,
                             int N) {
    __shared__ int s[256];
    int tid = threadIdx.x;
    int i = blockIdx.x * 256 + tid;
    int v = (i < N) ? cnt[i] : 0;
    s[tid] = v;
    __syncthreads();
    for (int off = 1; off < 256; off <<= 1) {
        int t = (tid >= off) ? s[tid - off] : 0;
        __syncthreads();
        s[tid] += t;
        __syncthreads();
    }
    if (i < N) {
        int excl = s[tid] - v + blocksum[blockIdx.x];
        rowptr[i] = excl;
        cursor[i] = excl;
    }
}

// elist[atomicAdd(&cursor[dst],1)] = src
__global__ void k_fill(const void* __restrict__ ei, int* __restrict__ cursor,
                       int* __restrict__ elist, const int* __restrict__ flag,
                       int E) {
    const bool is32 = (*flag != 0);
    long long i = (long long)blockIdx.x * blockDim.x + threadIdx.x;
    long long stride = (long long)gridDim.x * blockDim.x;
    if (is32) {
        const int* ei32 = (const int*)ei;
        for (; i < E; i += stride) {
            int s = ei32[i];
            int t = ei32[E + i];
            int slot = atomicAdd(&cursor[t], 1);
            elist[slot] = s;
        }
    } else {
        const long long* ei64 = (const long long*)ei;
        for (; i < E; i += stride) {
            int s = (int)ei64[i];
            int t = (int)ei64[E + i];
            int slot = atomicAdd(&cursor[t], 1);
            elist[slot] = s;
        }
    }
}

// y[n] = rsqrt(1+cnt[n]) * (x[n] @ W); dinv[n] stored.
// If out_seed != nullptr (fallback path) also seed out[n] = y[n].
__global__ void k_xw(const float* __restrict__ x, const float* __restrict__ W,
                     const int* __restrict__ cnt, float* __restrict__ dinv,
                     float* __restrict__ y, float* __restrict__ out_seed,
                     int N) {
    __shared__ float Wt[OUT_CH][IN_CH];  // transposed for float4 reads
    for (int i = threadIdx.x; i < IN_CH * OUT_CH; i += blockDim.x) {
        int k = i / OUT_CH, c = i - k * OUT_CH;
        Wt[c][k] = W[i];
    }
    __syncthreads();

    int n = blockIdx.x * blockDim.x + threadIdx.x;
    if (n >= N) return;

    float acc[OUT_CH];
#pragma unroll
    for (int c = 0; c < OUT_CH; ++c) acc[c] = 0.0f;

    const float4* xr = (const float4*)(x + (size_t)n * IN_CH);
#pragma unroll 4
    for (int k4 = 0; k4 < IN_CH / 4; ++k4) {
        float4 xv = xr[k4];
#pragma unroll
        for (int c = 0; c < OUT_CH; ++c) {
            float4 wv = *(const float4*)&Wt[c][k4 * 4];  // wave-uniform bcast
            acc[c] += xv.x * wv.x + xv.y * wv.y + xv.z * wv.z + xv.w * wv.w;
        }
    }

    float d = rsqrtf(1.0f + (float)cnt[n]);
    dinv[n] = d;
    float2* yr = (float2*)(y + (size_t)n * OUT_CH);
#pragma unroll
    for (int c2 = 0; c2 < OUT_CH / 2; ++c2) {
        float2 v;
        v.x = d * acc[2 * c2];
        v.y = d * acc[2 * c2 + 1];
        yr[c2] = v;
    }
    if (out_seed) {
        float2* orow = (float2*)(out_seed + (size_t)n * OUT_CH);
#pragma unroll
        for (int c2 = 0; c2 < OUT_CH / 2; ++c2) {
            float2 v;
            v.x = d * acc[2 * c2];
            v.y = d * acc[2 * c2 + 1];
            orow[c2] = v;
        }
    }
}

// 4 threads per node: walk the node's CSR bucket, gather+sum y[src],
// shfl-reduce over the 4 lanes, then out = dinv*(acc + y[n]) + b.
__global__ void k_gather(const int* __restrict__ rowptr,
                         const int* __restrict__ cnt,
                         const int* __restrict__ elist,
                         const float* __restrict__ y,
                         const float* __restrict__ dinv,
                         const float* __restrict__ b, float* __restrict__ out,
                         int N) {
    int gid = blockIdx.x * blockDim.x + threadIdx.x;
    int n = gid >> 2;
    int t = gid & 3;
    if (n >= N) return;

    int beg = rowptr[n];
    int c = cnt[n];

    float acc[OUT_CH];
#pragma unroll
    for (int k = 0; k < OUT_CH; ++k) acc[k] = 0.0f;

    for (int e = t; e < c; e += 4) {
        int s = elist[beg + e];
        const float2* yr = (const float2*)(y + (size_t)s * OUT_CH);
        float2 v0 = yr[0], v1 = yr[1], v2 = yr[2], v3 = yr[3], v4 = yr[4];
        acc[0] += v0.x; acc[1] += v0.y;
        acc[2] += v1.x; acc[3] += v1.y;
        acc[4] += v2.x; acc[5] += v2.y;
        acc[6] += v3.x; acc[7] += v3.y;
        acc[8] += v4.x; acc[9] += v4.y;
    }

    // reduce across the 4 consecutive lanes of this node
#pragma unroll
    for (int k = 0; k < OUT_CH; ++k) {
        acc[k] += __shfl_xor(acc[k], 1);
        acc[k] += __shfl_xor(acc[k], 2);
    }

    if (t == 0) {
        float d = dinv[n];
        const float2* yn = (const float2*)(y + (size_t)n * OUT_CH);
        float2* orow = (float2*)(out + (size_t)n * OUT_CH);
#pragma unroll
        for (int c2 = 0; c2 < OUT_CH / 2; ++c2) {
            float2 v = yn[c2];
            float2 o;
            o.x = d * (acc[2 * c2] + v.x) + b[2 * c2];
            o.y = d * (acc[2 * c2 + 1] + v.y) + b[2 * c2 + 1];
            orow[c2] = o;
        }
    }
}

// ============================================================================
// Fallback path (round-1 atomic scatter) — used only if ws_size is too small
// ============================================================================

__global__ void k_scatter(const void* __restrict__ ei,
                          const float* __restrict__ y, float* __restrict__ out,
                          const int* __restrict__ flag, int E) {
    const bool is32 = (*flag != 0);
    long long i = (long long)blockIdx.x * blockDim.x + threadIdx.x;
    long long stride = (long long)gridDim.x * blockDim.x;
    for (; i < E; i += stride) {
        long long s, t;
        if (is32) {
            const int* ei32 = (const int*)ei;
            s = ei32[i];
            t = ei32[E + i];
        } else {
            const long long* ei64 = (const long long*)ei;
            s = ei64[i];
            t = ei64[E + i];
        }
        const float2* yr = (const float2*)(y + s * OUT_CH);
        float2 v0 = yr[0], v1 = yr[1], v2 = yr[2], v3 = yr[3], v4 = yr[4];
        float* orow = out + t * OUT_CH;
        atomicAdd(&orow[0], v0.x);
        atomicAdd(&orow[1], v0.y);
        atomicAdd(&orow[2], v1.x);
        atomicAdd(&orow[3], v1.y);
        atomicAdd(&orow[4], v2.x);
        atomicAdd(&orow[5], v2.y);
        atomicAdd(&orow[6], v3.x);
        atomicAdd(&orow[7], v3.y);
        atomicAdd(&orow[8], v4.x);
        atomicAdd(&orow[9], v4.y);
    }
}

__global__ void k_final(const float* __restrict__ dinv,
                        const float* __restrict__ b, float* __restrict__ out,
                        int N) {
    int n = blockIdx.x * blockDim.x + threadIdx.x;
    if (n >= N) return;
    float d = dinv[n];
    float2* orow = (float2*)(out + (size_t)n * OUT_CH);
#pragma unroll
    for (int c2 = 0; c2 < OUT_CH / 2; ++c2) {
        float2 v = orow[c2];
        v.x = v.x * d + b[2 * c2];
        v.y = v.y * d + b[2 * c2 + 1];
        orow[c2] = v;
    }
}

// ============================================================================
// Launch
// ============================================================================

extern "C" void kernel_launch(void* const* d_in, const int* in_sizes, int n_in,
                              void* d_out, int out_size, void* d_ws,
                              size_t ws_size, hipStream_t stream) {
    const float* x = (const float*)d_in[0];
    const void* ei = d_in[1];
    const float* W = (const float*)d_in[2];
    const float* b = (const float*)d_in[3];
    float* out = (float*)d_out;

    int N = in_sizes[0] / IN_CH;  // 100000
    int E = in_sizes[1] / 2;      // 3200000

    int nblkN = (N + 255) / 256;          // node-grid (also #scan blocks)
    size_t needed =
        ((size_t)3 * N + 1024 + 2) * 4 +  // cnt, rowptr, cursor, blocksum, flag
        ((size_t)11 * N + 2) * 4 +        // dinv, y (+ alignment slack)
        (size_t)E * 4;                    // elist

    if (ws_size >= needed && nblkN <= 512) {
        // -------- CSR-gather path --------
        int* wsi = (int*)d_ws;
        int* cnt = wsi;                    // N
        int* rowptr = cnt + N;             // N
        int* cursor = rowptr + N;          // N
        int* blocksum = cursor + N;        // 1024
        int* flag = blocksum + 1024;       // 1
        size_t off = (size_t)3 * N + 1025;
        off = (off + 1) & ~(size_t)1;      // 8B-align for float2
        float* dinv = (float*)(wsi + off);       // N
        float* y = dinv + N;                     // 10N (off+N even -> aligned)
        int* elist = (int*)(y + (size_t)10 * N); // E

        k_zero_i<<<nblkN, 256, 0, stream>>>(cnt, N);
        k_detect<<<1, 256, 0, stream>>>((const unsigned int*)ei, flag, 8192);
        k_count<<<4096, 256, 0, stream>>>(ei, cnt, flag, E);
        k_scan_block<<<nblkN, 256, 0, stream>>>(cnt, blocksum, N);
        k_scan_top<<<1, 512, 0, stream>>>(blocksum, nblkN);
        k_scan_apply<<<nblkN, 256, 0, stream>>>(cnt, blocksum, rowptr, cursor, N);
        k_fill<<<4096, 256, 0, stream>>>(ei, cursor, elist, flag, E);
        k_xw<<<nblkN, 256, 0, stream>>>(x, W, cnt, dinv, y, nullptr, N);
        int gthreads = 4 * N;
        k_gather<<<(gthreads + 255) / 256, 256, 0, stream>>>(
            rowptr, cnt, elist, y, dinv, b, out, N);
    } else {
        // -------- fallback: atomic scatter (round-1) --------
        int* wsi = (int*)d_ws;
        int* cnt = wsi;                          // N
        int* flag = cnt + N;                     // 1
        size_t off = (size_t)N + 2;
        off = (off + 1) & ~(size_t)1;
        float* dinv = (float*)(wsi + off);       // N
        float* y = dinv + N;                     // 10N

        k_zero_i<<<nblkN, 256, 0, stream>>>(cnt, N);
        k_detect<<<1, 256, 0, stream>>>((const unsigned int*)ei, flag, 8192);
        k_count<<<4096, 256, 0, stream>>>(ei, cnt, flag, E);
        k_xw<<<nblkN, 256, 0, stream>>>(x, W, cnt, dinv, y, out, N);
        k_scatter<<<4096, 256, 0, stream>>>(ei, y, out, flag, E);
        k_final<<<nblkN, 256, 0, stream>>>(dinv, b, out, N);
    }
}

// Round 3
// 326.280 us; speedup vs baseline: 5.5183x; 1.5320x over previous
//
#include <hip/hip_runtime.h>

#define IN_CH 128
#define OUT_CH 10
#define SHIFT 7                    // nodes per bucket = 128
#define NPB 128
#define CHUNK 8192                 // edges per block in binning kernels

// ============================================================================
// Shared helpers
// ============================================================================

// Detect whether edge_index arrived as int64 or int32.
// For int64 (values < 2^17) every odd 32-bit word (high half) is zero.
// flag = 1 -> int32 data, flag = 0 -> int64 data. Deterministic.
__global__ void k_detect(const unsigned int* __restrict__ w, int* flag,
                         int nwords_check) {
    __shared__ int any_nz;
    if (threadIdx.x == 0) any_nz = 0;
    __syncthreads();
    int local = 0;
    for (int i = threadIdx.x; i < nwords_check; i += blockDim.x)
        if (w[2 * i + 1] != 0u) local = 1;
    if (local) atomicOr(&any_nz, 1);
    __syncthreads();
    if (threadIdx.x == 0) *flag = any_nz;
}

__global__ void k_zero_i(int* __restrict__ p, int n) {
    int i = blockIdx.x * blockDim.x + threadIdx.x;
    int stride = gridDim.x * blockDim.x;
    for (; i < n; i += stride) p[i] = 0;
}

__device__ __forceinline__ int load_dst(const void* ei, bool is32, long long E,
                                        long long i) {
    return is32 ? ((const int*)ei)[E + i] : (int)((const long long*)ei)[E + i];
}
__device__ __forceinline__ int load_src(const void* ei, bool is32, long long E,
                                        long long i) {
    return is32 ? ((const int*)ei)[i] : (int)((const long long*)ei)[i];
}

// ============================================================================
// Bucketed-gather path (primary)
// ============================================================================

// Per-chunk LDS histogram of buckets, flushed with one atomic per bucket.
__global__ void k_bincount(const void* __restrict__ ei,
                           const int* __restrict__ flag, int E,
                           int* __restrict__ bcnt, int NB) {
    __shared__ int h[1024];
    for (int i = threadIdx.x; i < NB; i += blockDim.x) h[i] = 0;
    __syncthreads();
    const bool is32 = (*flag != 0);
    long long base = (long long)blockIdx.x * CHUNK;
    int lim = (int)min((long long)CHUNK, (long long)E - base);
    for (int i = threadIdx.x; i < lim; i += blockDim.x) {
        int d = load_dst(ei, is32, E, base + i);
        atomicAdd(&h[d >> SHIFT], 1);
    }
    __syncthreads();
    for (int i = threadIdx.x; i < NB; i += blockDim.x)
        if (h[i]) atomicAdd(&bcnt[i], h[i]);
}

// Exclusive scan of bcnt[NB] (NB <= 1024) -> bbase, gcursor
__global__ void k_scanNB(const int* __restrict__ bcnt, int* __restrict__ bbase,
                         int* __restrict__ gcur, int NB) {
    __shared__ int s[1024];
    int tid = threadIdx.x;
    int v = (tid < NB) ? bcnt[tid] : 0;
    s[tid] = v;
    __syncthreads();
    for (int off = 1; off < 1024; off <<= 1) {
        int t = (tid >= off) ? s[tid - off] : 0;
        __syncthreads();
        s[tid] += t;
        __syncthreads();
    }
    if (tid < NB) {
        int e = s[tid] - v;
        bbase[tid] = e;
        gcur[tid] = e;
    }
}

// Per chunk: LDS hist -> reserve contiguous per-bucket runs via one global
// atomic per (block,bucket) -> write (src,dst) pairs into the runs.
__global__ void k_binfill(const void* __restrict__ ei,
                          const int* __restrict__ flag, int E,
                          int* __restrict__ gcur, int2* __restrict__ pairs,
                          int NB) {
    __shared__ int h[1024];
    __shared__ int cur[1024];
    for (int i = threadIdx.x; i < NB; i += blockDim.x) h[i] = 0;
    __syncthreads();
    const bool is32 = (*flag != 0);
    long long base = (long long)blockIdx.x * CHUNK;
    int lim = (int)min((long long)CHUNK, (long long)E - base);
    for (int i = threadIdx.x; i < lim; i += blockDim.x) {
        int d = load_dst(ei, is32, E, base + i);
        atomicAdd(&h[d >> SHIFT], 1);
    }
    __syncthreads();
    for (int i = threadIdx.x; i < NB; i += blockDim.x)
        cur[i] = h[i] ? atomicAdd(&gcur[i], h[i]) : 0;
    __syncthreads();
    for (int i = threadIdx.x; i < lim; i += blockDim.x) {
        int s = load_src(ei, is32, E, base + i);
        int d = load_dst(ei, is32, E, base + i);
        int slot = atomicAdd(&cur[d >> SHIFT], 1);
        int2 p;
        p.x = s;
        p.y = d;
        pairs[slot] = p;
    }
}

// One block per bucket: LDS histogram of its 128-node range -> dinv.
__global__ void k_deg_dinv(const int2* __restrict__ pairs,
                           const int* __restrict__ bbase,
                           const int* __restrict__ bcnt,
                           float* __restrict__ dinv, int N) {
    __shared__ int deg[NPB];
    int tid = threadIdx.x;
    if (tid < NPB) deg[tid] = 0;
    __syncthreads();
    int b = blockIdx.x;
    int beg = bbase[b], c = bcnt[b];
    for (int i = tid; i < c; i += blockDim.x) {
        int d = pairs[beg + i].y;
        atomicAdd(&deg[d & (NPB - 1)], 1);
    }
    __syncthreads();
    if (tid < NPB) {
        int n = b * NPB + tid;
        if (n < N) dinv[n] = rsqrtf(1.0f + (float)deg[tid]);
    }
}

// y[n] = dinv[n] * (x[n] @ W)
__global__ void k_xw(const float* __restrict__ x, const float* __restrict__ W,
                     const float* __restrict__ dinv, float* __restrict__ y,
                     int N) {
    __shared__ float Wt[OUT_CH][IN_CH];
    for (int i = threadIdx.x; i < IN_CH * OUT_CH; i += blockDim.x) {
        int k = i / OUT_CH, c = i - k * OUT_CH;
        Wt[c][k] = W[i];
    }
    __syncthreads();

    int n = blockIdx.x * blockDim.x + threadIdx.x;
    if (n >= N) return;

    float acc[OUT_CH];
#pragma unroll
    for (int c = 0; c < OUT_CH; ++c) acc[c] = 0.0f;

    const float4* xr = (const float4*)(x + (size_t)n * IN_CH);
#pragma unroll 4
    for (int k4 = 0; k4 < IN_CH / 4; ++k4) {
        float4 xv = xr[k4];
#pragma unroll
        for (int c = 0; c < OUT_CH; ++c) {
            float4 wv = *(const float4*)&Wt[c][k4 * 4];
            acc[c] += xv.x * wv.x + xv.y * wv.y + xv.z * wv.z + xv.w * wv.w;
        }
    }

    float d = dinv[n];
    float2* yr = (float2*)(y + (size_t)n * OUT_CH);
#pragma unroll
    for (int c2 = 0; c2 < OUT_CH / 2; ++c2) {
        float2 v;
        v.x = d * acc[2 * c2];
        v.y = d * acc[2 * c2 + 1];
        yr[c2] = v;
    }
}

// One block per bucket: stream pairs, gather y[src], ds_add_f32 into LDS
// rows, then out = dinv[n]*(acc + y[n]) + bias, coalesced, written once.
__global__ void k_accum(const int2* __restrict__ pairs,
                        const int* __restrict__ bbase,
                        const int* __restrict__ bcnt,
                        const float* __restrict__ y,
                        const float* __restrict__ dinv,
                        const float* __restrict__ bias,
                        float* __restrict__ out, int N) {
    __shared__ float acc[NPB * OUT_CH];  // 5 KB
    __shared__ float ldinv[NPB];
    int tid = threadIdx.x;
    for (int i = tid; i < NPB * OUT_CH; i += blockDim.x) acc[i] = 0.0f;
    int b = blockIdx.x;
    if (tid < NPB) {
        int n = b * NPB + tid;
        ldinv[tid] = (n < N) ? dinv[n] : 0.0f;
    }
    __syncthreads();

    int beg = bbase[b], c = bcnt[b];
    for (int i = tid; i < c; i += blockDim.x) {
        int2 p = pairs[beg + i];
        const float2* yr = (const float2*)(y + (size_t)p.x * OUT_CH);
        float2 v0 = yr[0], v1 = yr[1], v2 = yr[2], v3 = yr[3], v4 = yr[4];
        int r = (p.y & (NPB - 1)) * OUT_CH;
        atomicAdd(&acc[r + 0], v0.x);
        atomicAdd(&acc[r + 1], v0.y);
        atomicAdd(&acc[r + 2], v1.x);
        atomicAdd(&acc[r + 3], v1.y);
        atomicAdd(&acc[r + 4], v2.x);
        atomicAdd(&acc[r + 5], v2.y);
        atomicAdd(&acc[r + 6], v3.x);
        atomicAdd(&acc[r + 7], v3.y);
        atomicAdd(&acc[r + 8], v4.x);
        atomicAdd(&acc[r + 9], v4.y);
    }
    __syncthreads();

    for (int idx = tid; idx < NPB * OUT_CH; idx += blockDim.x) {
        int nl = idx / OUT_CH;
        int ch = idx - nl * OUT_CH;
        int n = b * NPB + nl;
        if (n < N) {
            float dn = ldinv[nl];
            out[(size_t)n * OUT_CH + ch] =
                dn * (acc[idx] + y[(size_t)n * OUT_CH + ch]) + bias[ch];
        }
    }
}

// ============================================================================
// Fallback path (round-1 atomic scatter) — used only if ws too small / N huge
// ============================================================================

__global__ void k_count_fb(const void* __restrict__ ei, int* __restrict__ cnt,
                           const int* __restrict__ flag, int E) {
    const bool is32 = (*flag != 0);
    long long i = (long long)blockIdx.x * blockDim.x + threadIdx.x;
    long long stride = (long long)gridDim.x * blockDim.x;
    for (; i < E; i += stride) atomicAdd(&cnt[load_dst(ei, is32, E, i)], 1);
}

__global__ void k_xw_fb(const float* __restrict__ x,
                        const float* __restrict__ W,
                        const int* __restrict__ cnt, float* __restrict__ dinv,
                        float* __restrict__ y, float* __restrict__ out_seed,
                        int N) {
    __shared__ float Wt[OUT_CH][IN_CH];
    for (int i = threadIdx.x; i < IN_CH * OUT_CH; i += blockDim.x) {
        int k = i / OUT_CH, c = i - k * OUT_CH;
        Wt[c][k] = W[i];
    }
    __syncthreads();
    int n = blockIdx.x * blockDim.x + threadIdx.x;
    if (n >= N) return;
    float acc[OUT_CH];
#pragma unroll
    for (int c = 0; c < OUT_CH; ++c) acc[c] = 0.0f;
    const float4* xr = (const float4*)(x + (size_t)n * IN_CH);
#pragma unroll 4
    for (int k4 = 0; k4 < IN_CH / 4; ++k4) {
        float4 xv = xr[k4];
#pragma unroll
        for (int c = 0; c < OUT_CH; ++c) {
            float4 wv = *(const float4*)&Wt[c][k4 * 4];
            acc[c] += xv.x * wv.x + xv.y * wv.y + xv.z * wv.z + xv.w * wv.w;
        }
    }
    float d = rsqrtf(1.0f + (float)cnt[n]);
    dinv[n] = d;
    float2* yr = (float2*)(y + (size_t)n * OUT_CH);
    float2* orow = (float2*)(out_seed + (size_t)n * OUT_CH);
#pragma unroll
    for (int c2 = 0; c2 < OUT_CH / 2; ++c2) {
        float2 v;
        v.x = d * acc[2 * c2];
        v.y = d * acc[2 * c2 + 1];
        yr[c2] = v;
        orow[c2] = v;
    }
}

__global__ void k_scatter_fb(const void* __restrict__ ei,
                             const float* __restrict__ y,
                             float* __restrict__ out,
                             const int* __restrict__ flag, int E) {
    const bool is32 = (*flag != 0);
    long long i = (long long)blockIdx.x * blockDim.x + threadIdx.x;
    long long stride = (long long)gridDim.x * blockDim.x;
    for (; i < E; i += stride) {
        long long s = load_src(ei, is32, E, i);
        long long t = load_dst(ei, is32, E, i);
        const float2* yr = (const float2*)(y + s * OUT_CH);
        float2 v0 = yr[0], v1 = yr[1], v2 = yr[2], v3 = yr[3], v4 = yr[4];
        float* orow = out + t * OUT_CH;
        atomicAdd(&orow[0], v0.x);
        atomicAdd(&orow[1], v0.y);
        atomicAdd(&orow[2], v1.x);
        atomicAdd(&orow[3], v1.y);
        atomicAdd(&orow[4], v2.x);
        atomicAdd(&orow[5], v2.y);
        atomicAdd(&orow[6], v3.x);
        atomicAdd(&orow[7], v3.y);
        atomicAdd(&orow[8], v4.x);
        atomicAdd(&orow[9], v4.y);
    }
}

__global__ void k_final_fb(const float* __restrict__ dinv,
                           const float* __restrict__ b,
                           float* __restrict__ out, int N) {
    int n = blockIdx.x * blockDim.x + threadIdx.x;
    if (n >= N) return;
    float d = dinv[n];
    float2* orow = (float2*)(out + (size_t)n * OUT_CH);
#pragma unroll
    for (int c2 = 0; c2 < OUT_CH / 2; ++c2) {
        float2 v = orow[c2];
        v.x = v.x * d + b[2 * c2];
        v.y = v.y * d + b[2 * c2 + 1];
        orow[c2] = v;
    }
}

// ============================================================================
// Launch
// ============================================================================

extern "C" void kernel_launch(void* const* d_in, const int* in_sizes, int n_in,
                              void* d_out, int out_size, void* d_ws,
                              size_t ws_size, hipStream_t stream) {
    const float* x = (const float*)d_in[0];
    const void* ei = d_in[1];
    const float* W = (const float*)d_in[2];
    const float* b = (const float*)d_in[3];
    float* out = (float*)d_out;

    int N = in_sizes[0] / IN_CH;  // 100000
    int E = in_sizes[1] / 2;      // 3200000

    int NB = (N + NPB - 1) / NPB;        // buckets (782)
    int nblkN = (N + 255) / 256;
    int nblkE = (E + CHUNK - 1) / CHUNK;

    // primary ws layout (4B units):
    //   bcnt[NB] | bbase[NB] | gcur[NB] | flag | pad | dinv[N] | y[10N] |
    //   pad | pairs[E] (int2)
    size_t off_dinv = ((size_t)3 * NB + 1 + 1) & ~(size_t)1;
    size_t off_y = (off_dinv + N + 1) & ~(size_t)1;
    size_t off_pairs = (off_y + (size_t)10 * N + 1) & ~(size_t)1;
    size_t needed = (off_pairs + (size_t)2 * E) * 4;

    if (ws_size >= needed && NB <= 1024) {
        int* wsi = (int*)d_ws;
        int* bcnt = wsi;
        int* bbase = bcnt + NB;
        int* gcur = bbase + NB;
        int* flag = gcur + NB;
        float* dinv = (float*)(wsi + off_dinv);
        float* y = (float*)(wsi + off_y);
        int2* pairs = (int2*)(wsi + off_pairs);

        k_zero_i<<<(NB + 255) / 256, 256, 0, stream>>>(bcnt, NB);
        k_detect<<<1, 256, 0, stream>>>((const unsigned int*)ei, flag, 8192);
        k_bincount<<<nblkE, 256, 0, stream>>>(ei, flag, E, bcnt, NB);
        k_scanNB<<<1, 1024, 0, stream>>>(bcnt, bbase, gcur, NB);
        k_binfill<<<nblkE, 256, 0, stream>>>(ei, flag, E, gcur, pairs, NB);
        k_deg_dinv<<<NB, 256, 0, stream>>>(pairs, bbase, bcnt, dinv, N);
        k_xw<<<nblkN, 256, 0, stream>>>(x, W, dinv, y, N);
        k_accum<<<NB, 256, 0, stream>>>(pairs, bbase, bcnt, y, dinv, b, out, N);
    } else {
        // -------- fallback: atomic scatter --------
        int* wsi = (int*)d_ws;
        int* cnt = wsi;                     // N
        int* flag = cnt + N;                // 1
        size_t off = ((size_t)N + 2) & ~(size_t)1;
        float* dinv = (float*)(wsi + off);  // N
        float* y = dinv + N;                // 10N

        k_zero_i<<<nblkN, 256, 0, stream>>>(cnt, N);
        k_detect<<<1, 256, 0, stream>>>((const unsigned int*)ei, flag, 8192);
        k_count_fb<<<4096, 256, 0, stream>>>(ei, cnt, flag, E);
        k_xw_fb<<<nblkN, 256, 0, stream>>>(x, W, cnt, dinv, y, out, N);
        k_scatter_fb<<<4096, 256, 0, stream>>>(ei, y, out, flag, E);
        k_final_fb<<<nblkN, 256, 0, stream>>>(dinv, b, out, N);
    }
}

// Round 4
// 291.612 us; speedup vs baseline: 6.1744x; 1.1189x over previous
//
#include <hip/hip_runtime.h>

#define IN_CH 128
#define OUT_CH 10
#define SHIFT 7                    // nodes per bucket = 128
#define NPB 128
#define ROWP 11                    // padded LDS row stride (gcd(11,32)=1)
#define CHUNK 8192                 // edges per block in binning kernels

// ============================================================================
// Shared helpers
// ============================================================================

// Detect whether edge_index arrived as int64 or int32 (odd words all zero
// for int64 values < 2^17). flag=1 -> int32, flag=0 -> int64. Deterministic.
__global__ void k_detect(const unsigned int* __restrict__ w, int* flag,
                         int nwords_check) {
    __shared__ int any_nz;
    if (threadIdx.x == 0) any_nz = 0;
    __syncthreads();
    int local = 0;
    for (int i = threadIdx.x; i < nwords_check; i += blockDim.x)
        if (w[2 * i + 1] != 0u) local = 1;
    if (local) atomicOr(&any_nz, 1);
    __syncthreads();
    if (threadIdx.x == 0) *flag = any_nz;
}

__global__ void k_zero_i(int* __restrict__ p, int n) {
    int i = blockIdx.x * blockDim.x + threadIdx.x;
    int stride = gridDim.x * blockDim.x;
    for (; i < n; i += stride) p[i] = 0;
}

__device__ __forceinline__ int load_dst(const void* ei, bool is32, long long E,
                                        long long i) {
    return is32 ? ((const int*)ei)[E + i] : (int)((const long long*)ei)[E + i];
}
__device__ __forceinline__ int load_src(const void* ei, bool is32, long long E,
                                        long long i) {
    return is32 ? ((const int*)ei)[i] : (int)((const long long*)ei)[i];
}

// ============================================================================
// Bucketed-gather path (primary)
// ============================================================================

// Per-chunk LDS histogram of buckets, flushed with one atomic per bucket.
__global__ void k_bincount(const void* __restrict__ ei,
                           const int* __restrict__ flag, int E,
                           int* __restrict__ bcnt, int NB) {
    __shared__ int h[1024];
    for (int i = threadIdx.x; i < NB; i += blockDim.x) h[i] = 0;
    __syncthreads();
    const bool is32 = (*flag != 0);
    long long base = (long long)blockIdx.x * CHUNK;
    int lim = (int)min((long long)CHUNK, (long long)E - base);
    for (int i = threadIdx.x; i < lim; i += blockDim.x) {
        int d = load_dst(ei, is32, E, base + i);
        atomicAdd(&h[d >> SHIFT], 1);
    }
    __syncthreads();
    for (int i = threadIdx.x; i < NB; i += blockDim.x)
        if (h[i]) atomicAdd(&bcnt[i], h[i]);
}

// Exclusive scan of bcnt[NB] (NB <= 1024) -> bbase, gcursor
__global__ void k_scanNB(const int* __restrict__ bcnt, int* __restrict__ bbase,
                         int* __restrict__ gcur, int NB) {
    __shared__ int s[1024];
    int tid = threadIdx.x;
    int v = (tid < NB) ? bcnt[tid] : 0;
    s[tid] = v;
    __syncthreads();
    for (int off = 1; off < 1024; off <<= 1) {
        int t = (tid >= off) ? s[tid - off] : 0;
        __syncthreads();
        s[tid] += t;
        __syncthreads();
    }
    if (tid < NB) {
        int e = s[tid] - v;
        bbase[tid] = e;
        gcur[tid] = e;
    }
}

// Per chunk: LDS hist -> reserve contiguous per-bucket runs via one global
// atomic per (block,bucket) -> write packed (src<<7 | dst&127) into the runs.
__global__ void k_binfill(const void* __restrict__ ei,
                          const int* __restrict__ flag, int E,
                          int* __restrict__ gcur, int* __restrict__ pairs,
                          int NB) {
    __shared__ int h[1024];
    __shared__ int cur[1024];
    for (int i = threadIdx.x; i < NB; i += blockDim.x) h[i] = 0;
    __syncthreads();
    const bool is32 = (*flag != 0);
    long long base = (long long)blockIdx.x * CHUNK;
    int lim = (int)min((long long)CHUNK, (long long)E - base);
    for (int i = threadIdx.x; i < lim; i += blockDim.x) {
        int d = load_dst(ei, is32, E, base + i);
        atomicAdd(&h[d >> SHIFT], 1);
    }
    __syncthreads();
    for (int i = threadIdx.x; i < NB; i += blockDim.x)
        cur[i] = h[i] ? atomicAdd(&gcur[i], h[i]) : 0;
    __syncthreads();
    for (int i = threadIdx.x; i < lim; i += blockDim.x) {
        int s = load_src(ei, is32, E, base + i);
        int d = load_dst(ei, is32, E, base + i);
        int slot = atomicAdd(&cur[d >> SHIFT], 1);
        pairs[slot] = (int)(((unsigned)s << SHIFT) | (unsigned)(d & (NPB - 1)));
    }
}

// One block per bucket: LDS histogram of its 128-node range -> dinv.
__global__ void k_deg_dinv(const int* __restrict__ pairs,
                           const int* __restrict__ bbase,
                           const int* __restrict__ bcnt,
                           float* __restrict__ dinv, int N) {
    __shared__ int deg[NPB];
    int tid = threadIdx.x;
    if (tid < NPB) deg[tid] = 0;
    __syncthreads();
    int b = blockIdx.x;
    int beg = bbase[b], c = bcnt[b];
    for (int i = tid; i < c; i += blockDim.x)
        atomicAdd(&deg[pairs[beg + i] & (NPB - 1)], 1);
    __syncthreads();
    if (tid < NPB) {
        int n = b * NPB + tid;
        if (n < N) dinv[n] = rsqrtf(1.0f + (float)deg[tid]);
    }
}

// y[n] = dinv[n] * (x[n] @ W)
__global__ void k_xw(const float* __restrict__ x, const float* __restrict__ W,
                     const float* __restrict__ dinv, float* __restrict__ y,
                     int N) {
    __shared__ float Wt[OUT_CH][IN_CH];
    for (int i = threadIdx.x; i < IN_CH * OUT_CH; i += blockDim.x) {
        int k = i / OUT_CH, c = i - k * OUT_CH;
        Wt[c][k] = W[i];
    }
    __syncthreads();

    int n = blockIdx.x * blockDim.x + threadIdx.x;
    if (n >= N) return;

    float acc[OUT_CH];
#pragma unroll
    for (int c = 0; c < OUT_CH; ++c) acc[c] = 0.0f;

    const float4* xr = (const float4*)(x + (size_t)n * IN_CH);
#pragma unroll 4
    for (int k4 = 0; k4 < IN_CH / 4; ++k4) {
        float4 xv = xr[k4];
#pragma unroll
        for (int c = 0; c < OUT_CH; ++c) {
            float4 wv = *(const float4*)&Wt[c][k4 * 4];
            acc[c] += xv.x * wv.x + xv.y * wv.y + xv.z * wv.z + xv.w * wv.w;
        }
    }

    float d = dinv[n];
    float2* yr = (float2*)(y + (size_t)n * OUT_CH);
#pragma unroll
    for (int c2 = 0; c2 < OUT_CH / 2; ++c2) {
        float2 v;
        v.x = d * acc[2 * c2];
        v.y = d * acc[2 * c2 + 1];
        yr[c2] = v;
    }
}

// SPLIT sub-blocks per bucket: each accumulates a slice of the bucket's
// packed pairs into private (bank-padded) LDS, then flushes a coalesced
// 128x10 partial to ws. No global atomics.
__global__ void k_accum(const int* __restrict__ pairs,
                        const int* __restrict__ bbase,
                        const int* __restrict__ bcnt,
                        const float* __restrict__ y, float* __restrict__ part,
                        int split_log) {
    __shared__ float acc[NPB * ROWP];  // 5632 B, stride 11 -> all 32 banks
    int tid = threadIdx.x;
    for (int i = tid; i < NPB * ROWP; i += 256) acc[i] = 0.0f;
    __syncthreads();

    int b = blockIdx.x >> split_log;
    int s = blockIdx.x & ((1 << split_log) - 1);
    int beg = bbase[b];
    int c = bcnt[b];
    int lo = beg + (int)(((long long)c * s) >> split_log);
    int hi = beg + (int)(((long long)c * (s + 1)) >> split_log);

    for (int i = lo + tid; i < hi; i += 256) {
        unsigned pp = (unsigned)pairs[i];
        int ra = (int)(pp & (NPB - 1)) * ROWP;
        const float2* yr = (const float2*)(y + (size_t)(pp >> SHIFT) * OUT_CH);
        float2 v0 = yr[0], v1 = yr[1], v2 = yr[2], v3 = yr[3], v4 = yr[4];
        atomicAdd(&acc[ra + 0], v0.x);
        atomicAdd(&acc[ra + 1], v0.y);
        atomicAdd(&acc[ra + 2], v1.x);
        atomicAdd(&acc[ra + 3], v1.y);
        atomicAdd(&acc[ra + 4], v2.x);
        atomicAdd(&acc[ra + 5], v2.y);
        atomicAdd(&acc[ra + 6], v3.x);
        atomicAdd(&acc[ra + 7], v3.y);
        atomicAdd(&acc[ra + 8], v4.x);
        atomicAdd(&acc[ra + 9], v4.y);
    }
    __syncthreads();

    float* dst = part + (size_t)blockIdx.x * (NPB * OUT_CH);
    for (int i = tid; i < NPB * OUT_CH; i += 256) {
        int r = i / OUT_CH;
        dst[i] = acc[r * ROWP + (i - r * OUT_CH)];
    }
}

// out[n][ch] = dinv[n] * (sum_partials + y[n][ch]) + bias[ch]
__global__ void k_merge(const float* __restrict__ part,
                        const float* __restrict__ y,
                        const float* __restrict__ dinv,
                        const float* __restrict__ bias,
                        float* __restrict__ out, int N, int split_log) {
    int idx = blockIdx.x * blockDim.x + threadIdx.x;
    if (idx >= N * OUT_CH) return;
    int n = idx / OUT_CH;
    int ch = idx - n * OUT_CH;
    int b = n >> SHIFT;
    int local = (n & (NPB - 1)) * OUT_CH + ch;
    int split = 1 << split_log;
    size_t base_slot = (size_t)(b << split_log);
    float s = 0.0f;
    for (int ss = 0; ss < split; ++ss)
        s += part[(base_slot + ss) * (NPB * OUT_CH) + local];
    out[idx] = dinv[n] * (s + y[idx]) + bias[ch];
}

// ============================================================================
// Fallback path (atomic scatter) — used only if ws too small / N too large
// ============================================================================

__global__ void k_count_fb(const void* __restrict__ ei, int* __restrict__ cnt,
                           const int* __restrict__ flag, int E) {
    const bool is32 = (*flag != 0);
    long long i = (long long)blockIdx.x * blockDim.x + threadIdx.x;
    long long stride = (long long)gridDim.x * blockDim.x;
    for (; i < E; i += stride) atomicAdd(&cnt[load_dst(ei, is32, E, i)], 1);
}

__global__ void k_xw_fb(const float* __restrict__ x,
                        const float* __restrict__ W,
                        const int* __restrict__ cnt, float* __restrict__ dinv,
                        float* __restrict__ y, float* __restrict__ out_seed,
                        int N) {
    __shared__ float Wt[OUT_CH][IN_CH];
    for (int i = threadIdx.x; i < IN_CH * OUT_CH; i += blockDim.x) {
        int k = i / OUT_CH, c = i - k * OUT_CH;
        Wt[c][k] = W[i];
    }
    __syncthreads();
    int n = blockIdx.x * blockDim.x + threadIdx.x;
    if (n >= N) return;
    float acc[OUT_CH];
#pragma unroll
    for (int c = 0; c < OUT_CH; ++c) acc[c] = 0.0f;
    const float4* xr = (const float4*)(x + (size_t)n * IN_CH);
#pragma unroll 4
    for (int k4 = 0; k4 < IN_CH / 4; ++k4) {
        float4 xv = xr[k4];
#pragma unroll
        for (int c = 0; c < OUT_CH; ++c) {
            float4 wv = *(const float4*)&Wt[c][k4 * 4];
            acc[c] += xv.x * wv.x + xv.y * wv.y + xv.z * wv.z + xv.w * wv.w;
        }
    }
    float d = rsqrtf(1.0f + (float)cnt[n]);
    dinv[n] = d;
    float2* yr = (float2*)(y + (size_t)n * OUT_CH);
    float2* orow = (float2*)(out_seed + (size_t)n * OUT_CH);
#pragma unroll
    for (int c2 = 0; c2 < OUT_CH / 2; ++c2) {
        float2 v;
        v.x = d * acc[2 * c2];
        v.y = d * acc[2 * c2 + 1];
        yr[c2] = v;
        orow[c2] = v;
    }
}

__global__ void k_scatter_fb(const void* __restrict__ ei,
                             const float* __restrict__ y,
                             float* __restrict__ out,
                             const int* __restrict__ flag, int E) {
    const bool is32 = (*flag != 0);
    long long i = (long long)blockIdx.x * blockDim.x + threadIdx.x;
    long long stride = (long long)gridDim.x * blockDim.x;
    for (; i < E; i += stride) {
        long long s = load_src(ei, is32, E, i);
        long long t = load_dst(ei, is32, E, i);
        const float2* yr = (const float2*)(y + s * OUT_CH);
        float2 v0 = yr[0], v1 = yr[1], v2 = yr[2], v3 = yr[3], v4 = yr[4];
        float* orow = out + t * OUT_CH;
        atomicAdd(&orow[0], v0.x);
        atomicAdd(&orow[1], v0.y);
        atomicAdd(&orow[2], v1.x);
        atomicAdd(&orow[3], v1.y);
        atomicAdd(&orow[4], v2.x);
        atomicAdd(&orow[5], v2.y);
        atomicAdd(&orow[6], v3.x);
        atomicAdd(&orow[7], v3.y);
        atomicAdd(&orow[8], v4.x);
        atomicAdd(&orow[9], v4.y);
    }
}

__global__ void k_final_fb(const float* __restrict__ dinv,
                           const float* __restrict__ b,
                           float* __restrict__ out, int N) {
    int n = blockIdx.x * blockDim.x + threadIdx.x;
    if (n >= N) return;
    float d = dinv[n];
    float2* orow = (float2*)(out + (size_t)n * OUT_CH);
#pragma unroll
    for (int c2 = 0; c2 < OUT_CH / 2; ++c2) {
        float2 v = orow[c2];
        v.x = v.x * d + b[2 * c2];
        v.y = v.y * d + b[2 * c2 + 1];
        orow[c2] = v;
    }
}

// ============================================================================
// Launch
// ============================================================================

extern "C" void kernel_launch(void* const* d_in, const int* in_sizes, int n_in,
                              void* d_out, int out_size, void* d_ws,
                              size_t ws_size, hipStream_t stream) {
    const float* x = (const float*)d_in[0];
    const void* ei = d_in[1];
    const float* W = (const float*)d_in[2];
    const float* b = (const float*)d_in[3];
    float* out = (float*)d_out;

    int N = in_sizes[0] / IN_CH;  // 100000
    int E = in_sizes[1] / 2;      // 3200000

    int NB = (N + NPB - 1) / NPB;  // buckets (782)
    int nblkN = (N + 255) / 256;
    int nblkE = (E + CHUNK - 1) / CHUNK;

    // primary ws layout (4B units):
    //   bcnt[NB] | bbase[NB] | gcur[NB] | flag | pad | dinv[N] | y[10N] |
    //   pairs[E] (packed int) | part[NB * SPLIT * 1280]
    size_t off_dinv = ((size_t)3 * NB + 1 + 1) & ~(size_t)1;
    size_t off_y = (off_dinv + (size_t)N + 1) & ~(size_t)1;
    size_t off_pairs = off_y + (size_t)10 * N;
    size_t off_part = off_pairs + (size_t)E;

    // adaptive split: largest of {8,4,2,1} whose partial buffer fits in ws
    int split_log = -1;
    for (int sl = 3; sl >= 0; --sl) {
        size_t needed =
            (off_part + ((size_t)NB << sl) * (NPB * OUT_CH)) * 4;
        if (ws_size >= needed) {
            split_log = sl;
            break;
        }
    }

    if (split_log >= 0 && NB <= 1024 && N <= (1 << 24)) {
        int* wsi = (int*)d_ws;
        int* bcnt = wsi;
        int* bbase = bcnt + NB;
        int* gcur = bbase + NB;
        int* flag = gcur + NB;
        float* dinv = (float*)(wsi + off_dinv);
        float* y = (float*)(wsi + off_y);
        int* pairs = wsi + off_pairs;
        float* part = (float*)(wsi + off_part);

        k_zero_i<<<(NB + 255) / 256, 256, 0, stream>>>(bcnt, NB);
        k_detect<<<1, 256, 0, stream>>>((const unsigned int*)ei, flag, 8192);
        k_bincount<<<nblkE, 256, 0, stream>>>(ei, flag, E, bcnt, NB);
        k_scanNB<<<1, 1024, 0, stream>>>(bcnt, bbase, gcur, NB);
        k_binfill<<<nblkE, 256, 0, stream>>>(ei, flag, E, gcur, pairs, NB);
        k_deg_dinv<<<NB, 256, 0, stream>>>(pairs, bbase, bcnt, dinv, N);
        k_xw<<<nblkN, 256, 0, stream>>>(x, W, dinv, y, N);
        k_accum<<<NB << split_log, 256, 0, stream>>>(pairs, bbase, bcnt, y,
                                                     part, split_log);
        int mthreads = N * OUT_CH;
        k_merge<<<(mthreads + 255) / 256, 256, 0, stream>>>(part, y, dinv, b,
                                                            out, N, split_log);
    } else {
        // -------- fallback: atomic scatter --------
        int* wsi = (int*)d_ws;
        int* cnt = wsi;                     // N
        int* flag = cnt + N;                // 1
        size_t off = ((size_t)N + 2) & ~(size_t)1;
        float* dinv = (float*)(wsi + off);  // N
        float* y = dinv + N;                // 10N

        k_zero_i<<<nblkN, 256, 0, stream>>>(cnt, N);
        k_detect<<<1, 256, 0, stream>>>((const unsigned int*)ei, flag, 8192);
        k_count_fb<<<4096, 256, 0, stream>>>(ei, cnt, flag, E);
        k_xw_fb<<<nblkN, 256, 0, stream>>>(x, W, cnt, dinv, y, out, N);
        k_scatter_fb<<<4096, 256, 0, stream>>>(ei, y, out, flag, E);
        k_final_fb<<<nblkN, 256, 0, stream>>>(dinv, b, out, N);
    }
}

// Round 5
// 290.953 us; speedup vs baseline: 6.1883x; 1.0023x over previous
//
#include <hip/hip_runtime.h>

#define IN_CH 128
#define OUT_CH 10
#define YPAD 16                    // y row padded to 64 B (one cache line)
#define SHIFT 7                    // nodes per bucket = 128
#define NPB 128
#define ROWP 11                    // padded LDS row stride (gcd(11,32)=1)
#define CHUNK 8192                 // edges per block in binning kernels

// ============================================================================
// Shared helpers
// ============================================================================

// Detect whether edge_index arrived as int64 or int32 (odd words all zero
// for int64 values < 2^17). flag=1 -> int32, flag=0 -> int64. Deterministic.
__global__ void k_detect(const unsigned int* __restrict__ w, int* flag,
                         int nwords_check) {
    __shared__ int any_nz;
    if (threadIdx.x == 0) any_nz = 0;
    __syncthreads();
    int local = 0;
    for (int i = threadIdx.x; i < nwords_check; i += blockDim.x)
        if (w[2 * i + 1] != 0u) local = 1;
    if (local) atomicOr(&any_nz, 1);
    __syncthreads();
    if (threadIdx.x == 0) *flag = any_nz;
}

__global__ void k_zero_i(int* __restrict__ p, int n) {
    int i = blockIdx.x * blockDim.x + threadIdx.x;
    int stride = gridDim.x * blockDim.x;
    for (; i < n; i += stride) p[i] = 0;
}

__device__ __forceinline__ int load_dst(const void* ei, bool is32, long long E,
                                        long long i) {
    return is32 ? ((const int*)ei)[E + i] : (int)((const long long*)ei)[E + i];
}
__device__ __forceinline__ int load_src(const void* ei, bool is32, long long E,
                                        long long i) {
    return is32 ? ((const int*)ei)[i] : (int)((const long long*)ei)[i];
}

// ============================================================================
// Bucketed-gather path (primary)
// ============================================================================

// Per-chunk LDS histogram of buckets, flushed with one atomic per bucket.
__global__ void k_bincount(const void* __restrict__ ei,
                           const int* __restrict__ flag, int E,
                           int* __restrict__ bcnt, int NB) {
    __shared__ int h[1024];
    for (int i = threadIdx.x; i < NB; i += blockDim.x) h[i] = 0;
    __syncthreads();
    const bool is32 = (*flag != 0);
    long long base = (long long)blockIdx.x * CHUNK;
    int lim = (int)min((long long)CHUNK, (long long)E - base);
    for (int i = threadIdx.x; i < lim; i += blockDim.x) {
        int d = load_dst(ei, is32, E, base + i);
        atomicAdd(&h[d >> SHIFT], 1);
    }
    __syncthreads();
    for (int i = threadIdx.x; i < NB; i += blockDim.x)
        if (h[i]) atomicAdd(&bcnt[i], h[i]);
}

// Exclusive scan of bcnt[NB] (NB <= 1024) -> bbase, gcursor
__global__ void k_scanNB(const int* __restrict__ bcnt, int* __restrict__ bbase,
                         int* __restrict__ gcur, int NB) {
    __shared__ int s[1024];
    int tid = threadIdx.x;
    int v = (tid < NB) ? bcnt[tid] : 0;
    s[tid] = v;
    __syncthreads();
    for (int off = 1; off < 1024; off <<= 1) {
        int t = (tid >= off) ? s[tid - off] : 0;
        __syncthreads();
        s[tid] += t;
        __syncthreads();
    }
    if (tid < NB) {
        int e = s[tid] - v;
        bbase[tid] = e;
        gcur[tid] = e;
    }
}

// Per chunk: LDS hist -> reserve contiguous per-bucket runs via one global
// atomic per (block,bucket) -> write packed (src<<7 | dst&127) into the runs.
__global__ void k_binfill(const void* __restrict__ ei,
                          const int* __restrict__ flag, int E,
                          int* __restrict__ gcur, int* __restrict__ pairs,
                          int NB) {
    __shared__ int h[1024];
    __shared__ int cur[1024];
    for (int i = threadIdx.x; i < NB; i += blockDim.x) h[i] = 0;
    __syncthreads();
    const bool is32 = (*flag != 0);
    long long base = (long long)blockIdx.x * CHUNK;
    int lim = (int)min((long long)CHUNK, (long long)E - base);
    for (int i = threadIdx.x; i < lim; i += blockDim.x) {
        int d = load_dst(ei, is32, E, base + i);
        atomicAdd(&h[d >> SHIFT], 1);
    }
    __syncthreads();
    for (int i = threadIdx.x; i < NB; i += blockDim.x)
        cur[i] = h[i] ? atomicAdd(&gcur[i], h[i]) : 0;
    __syncthreads();
    for (int i = threadIdx.x; i < lim; i += blockDim.x) {
        int s = load_src(ei, is32, E, base + i);
        int d = load_dst(ei, is32, E, base + i);
        int slot = atomicAdd(&cur[d >> SHIFT], 1);
        pairs[slot] = (int)(((unsigned)s << SHIFT) | (unsigned)(d & (NPB - 1)));
    }
}

// One block per bucket: LDS histogram of its 128-node range -> dinv.
__global__ void k_deg_dinv(const int* __restrict__ pairs,
                           const int* __restrict__ bbase,
                           const int* __restrict__ bcnt,
                           float* __restrict__ dinv, int N) {
    __shared__ int deg[NPB];
    int tid = threadIdx.x;
    if (tid < NPB) deg[tid] = 0;
    __syncthreads();
    int b = blockIdx.x;
    int beg = bbase[b], c = bcnt[b];
    for (int i = tid; i < c; i += blockDim.x)
        atomicAdd(&deg[pairs[beg + i] & (NPB - 1)], 1);
    __syncthreads();
    if (tid < NPB) {
        int n = b * NPB + tid;
        if (n < N) dinv[n] = rsqrtf(1.0f + (float)deg[tid]);
    }
}

// y[n] = dinv[n] * (x[n] @ W), row padded to YPAD floats (64 B aligned)
__global__ void k_xw(const float* __restrict__ x, const float* __restrict__ W,
                     const float* __restrict__ dinv, float* __restrict__ y,
                     int N) {
    __shared__ float Wt[OUT_CH][IN_CH];
    for (int i = threadIdx.x; i < IN_CH * OUT_CH; i += blockDim.x) {
        int k = i / OUT_CH, c = i - k * OUT_CH;
        Wt[c][k] = W[i];
    }
    __syncthreads();

    int n = blockIdx.x * blockDim.x + threadIdx.x;
    if (n >= N) return;

    float acc[OUT_CH];
#pragma unroll
    for (int c = 0; c < OUT_CH; ++c) acc[c] = 0.0f;

    const float4* xr = (const float4*)(x + (size_t)n * IN_CH);
#pragma unroll 4
    for (int k4 = 0; k4 < IN_CH / 4; ++k4) {
        float4 xv = xr[k4];
#pragma unroll
        for (int c = 0; c < OUT_CH; ++c) {
            float4 wv = *(const float4*)&Wt[c][k4 * 4];
            acc[c] += xv.x * wv.x + xv.y * wv.y + xv.z * wv.z + xv.w * wv.w;
        }
    }

    float d = dinv[n];
    float4* yr = (float4*)(y + (size_t)n * YPAD);
    float4 o0, o1;
    o0.x = d * acc[0]; o0.y = d * acc[1]; o0.z = d * acc[2]; o0.w = d * acc[3];
    o1.x = d * acc[4]; o1.y = d * acc[5]; o1.z = d * acc[6]; o1.w = d * acc[7];
    yr[0] = o0;
    yr[1] = o1;
    float2 o2;
    o2.x = d * acc[8]; o2.y = d * acc[9];
    ((float2*)yr)[4] = o2;
}

// 4 blocks per bucket: block (b,q) scans bucket b's pairs but gathers only
// sources in quadrant q (= floor(src*4/N)). Since XCD = blockIdx%8 and
// blockIdx = 4b+q, each XCD touches a single 1/4 slice of y -> L2-resident
// gathers, each exactly one 64 B line. Partials flushed coalesced, no
// global atomics.
__global__ void k_accum(const int* __restrict__ pairs,
                        const int* __restrict__ bbase,
                        const int* __restrict__ bcnt,
                        const float* __restrict__ y, float* __restrict__ part,
                        float qscale) {
    __shared__ float acc[NPB * ROWP];  // stride 11 -> all 32 banks
    int tid = threadIdx.x;
    for (int i = tid; i < NPB * ROWP; i += 256) acc[i] = 0.0f;
    __syncthreads();

    int b = blockIdx.x >> 2;
    int myq = blockIdx.x & 3;
    int beg = bbase[b];
    int end = beg + bcnt[b];

    for (int i = beg + tid; i < end; i += 256) {
        unsigned pp = (unsigned)pairs[i];
        unsigned src = pp >> SHIFT;
        int q = (int)((float)src * qscale);
        q = q > 3 ? 3 : q;
        if (q == myq) {
            const float4* yr = (const float4*)(y + (size_t)src * YPAD);
            float4 v0 = yr[0];
            float4 v1 = yr[1];
            float2 v2 = ((const float2*)yr)[4];
            int ra = (int)(pp & (NPB - 1)) * ROWP;
            atomicAdd(&acc[ra + 0], v0.x);
            atomicAdd(&acc[ra + 1], v0.y);
            atomicAdd(&acc[ra + 2], v0.z);
            atomicAdd(&acc[ra + 3], v0.w);
            atomicAdd(&acc[ra + 4], v1.x);
            atomicAdd(&acc[ra + 5], v1.y);
            atomicAdd(&acc[ra + 6], v1.z);
            atomicAdd(&acc[ra + 7], v1.w);
            atomicAdd(&acc[ra + 8], v2.x);
            atomicAdd(&acc[ra + 9], v2.y);
        }
    }
    __syncthreads();

    float* dst = part + (size_t)blockIdx.x * (NPB * OUT_CH);
    for (int i = tid; i < NPB * OUT_CH; i += 256) {
        int r = i / OUT_CH;
        dst[i] = acc[r * ROWP + (i - r * OUT_CH)];
    }
}

// out[n][ch] = dinv[n] * (sum of 4 quadrant partials + y[n][ch]) + bias[ch]
__global__ void k_merge(const float* __restrict__ part,
                        const float* __restrict__ y,
                        const float* __restrict__ dinv,
                        const float* __restrict__ bias,
                        float* __restrict__ out, int N) {
    int idx = blockIdx.x * blockDim.x + threadIdx.x;
    if (idx >= N * OUT_CH) return;
    int n = idx / OUT_CH;
    int ch = idx - n * OUT_CH;
    int b = n >> SHIFT;
    int local = (n & (NPB - 1)) * OUT_CH + ch;
    size_t base_slot = (size_t)(b << 2);
    float s = part[(base_slot + 0) * (NPB * OUT_CH) + local] +
              part[(base_slot + 1) * (NPB * OUT_CH) + local] +
              part[(base_slot + 2) * (NPB * OUT_CH) + local] +
              part[(base_slot + 3) * (NPB * OUT_CH) + local];
    out[idx] = dinv[n] * (s + y[(size_t)n * YPAD + ch]) + bias[ch];
}

// ============================================================================
// Fallback path (atomic scatter) — used only if ws too small / N too large
// ============================================================================

__global__ void k_count_fb(const void* __restrict__ ei, int* __restrict__ cnt,
                           const int* __restrict__ flag, int E) {
    const bool is32 = (*flag != 0);
    long long i = (long long)blockIdx.x * blockDim.x + threadIdx.x;
    long long stride = (long long)gridDim.x * blockDim.x;
    for (; i < E; i += stride) atomicAdd(&cnt[load_dst(ei, is32, E, i)], 1);
}

__global__ void k_xw_fb(const float* __restrict__ x,
                        const float* __restrict__ W,
                        const int* __restrict__ cnt, float* __restrict__ dinv,
                        float* __restrict__ y, float* __restrict__ out_seed,
                        int N) {
    __shared__ float Wt[OUT_CH][IN_CH];
    for (int i = threadIdx.x; i < IN_CH * OUT_CH; i += blockDim.x) {
        int k = i / OUT_CH, c = i - k * OUT_CH;
        Wt[c][k] = W[i];
    }
    __syncthreads();
    int n = blockIdx.x * blockDim.x + threadIdx.x;
    if (n >= N) return;
    float acc[OUT_CH];
#pragma unroll
    for (int c = 0; c < OUT_CH; ++c) acc[c] = 0.0f;
    const float4* xr = (const float4*)(x + (size_t)n * IN_CH);
#pragma unroll 4
    for (int k4 = 0; k4 < IN_CH / 4; ++k4) {
        float4 xv = xr[k4];
#pragma unroll
        for (int c = 0; c < OUT_CH; ++c) {
            float4 wv = *(const float4*)&Wt[c][k4 * 4];
            acc[c] += xv.x * wv.x + xv.y * wv.y + xv.z * wv.z + xv.w * wv.w;
        }
    }
    float d = rsqrtf(1.0f + (float)cnt[n]);
    dinv[n] = d;
    float2* yr = (float2*)(y + (size_t)n * OUT_CH);
    float2* orow = (float2*)(out_seed + (size_t)n * OUT_CH);
#pragma unroll
    for (int c2 = 0; c2 < OUT_CH / 2; ++c2) {
        float2 v;
        v.x = d * acc[2 * c2];
        v.y = d * acc[2 * c2 + 1];
        yr[c2] = v;
        orow[c2] = v;
    }
}

__global__ void k_scatter_fb(const void* __restrict__ ei,
                             const float* __restrict__ y,
                             float* __restrict__ out,
                             const int* __restrict__ flag, int E) {
    const bool is32 = (*flag != 0);
    long long i = (long long)blockIdx.x * blockDim.x + threadIdx.x;
    long long stride = (long long)gridDim.x * blockDim.x;
    for (; i < E; i += stride) {
        long long s = load_src(ei, is32, E, i);
        long long t = load_dst(ei, is32, E, i);
        const float2* yr = (const float2*)(y + s * OUT_CH);
        float2 v0 = yr[0], v1 = yr[1], v2 = yr[2], v3 = yr[3], v4 = yr[4];
        float* orow = out + t * OUT_CH;
        atomicAdd(&orow[0], v0.x);
        atomicAdd(&orow[1], v0.y);
        atomicAdd(&orow[2], v1.x);
        atomicAdd(&orow[3], v1.y);
        atomicAdd(&orow[4], v2.x);
        atomicAdd(&orow[5], v2.y);
        atomicAdd(&orow[6], v3.x);
        atomicAdd(&orow[7], v3.y);
        atomicAdd(&orow[8], v4.x);
        atomicAdd(&orow[9], v4.y);
    }
}

__global__ void k_final_fb(const float* __restrict__ dinv,
                           const float* __restrict__ b,
                           float* __restrict__ out, int N) {
    int n = blockIdx.x * blockDim.x + threadIdx.x;
    if (n >= N) return;
    float d = dinv[n];
    float2* orow = (float2*)(out + (size_t)n * OUT_CH);
#pragma unroll
    for (int c2 = 0; c2 < OUT_CH / 2; ++c2) {
        float2 v = orow[c2];
        v.x = v.x * d + b[2 * c2];
        v.y = v.y * d + b[2 * c2 + 1];
        orow[c2] = v;
    }
}

// ============================================================================
// Launch
// ============================================================================

extern "C" void kernel_launch(void* const* d_in, const int* in_sizes, int n_in,
                              void* d_out, int out_size, void* d_ws,
                              size_t ws_size, hipStream_t stream) {
    const float* x = (const float*)d_in[0];
    const void* ei = d_in[1];
    const float* W = (const float*)d_in[2];
    const float* b = (const float*)d_in[3];
    float* out = (float*)d_out;

    int N = in_sizes[0] / IN_CH;  // 100000
    int E = in_sizes[1] / 2;      // 3200000

    int NB = (N + NPB - 1) / NPB;  // buckets (782)
    int nblkN = (N + 255) / 256;
    int nblkE = (E + CHUNK - 1) / CHUNK;

    // primary ws layout (4B units):
    //   bcnt[NB] | bbase[NB] | gcur[NB] | flag | pad16 | dinv[N] | pad16 |
    //   y[YPAD*N] (64B-aligned rows) | pairs[E] | pad16 | part[NB*4*1280]
    size_t off_dinv = (((size_t)3 * NB + 1) + 15) & ~(size_t)15;
    size_t off_y = ((off_dinv + (size_t)N) + 15) & ~(size_t)15;
    size_t off_pairs = off_y + (size_t)YPAD * N;
    size_t off_part = ((off_pairs + (size_t)E) + 15) & ~(size_t)15;
    size_t needed = (off_part + ((size_t)NB * 4) * (NPB * OUT_CH)) * 4;

    if (ws_size >= needed && NB <= 1024 && N <= (1 << 24)) {
        int* wsi = (int*)d_ws;
        int* bcnt = wsi;
        int* bbase = bcnt + NB;
        int* gcur = bbase + NB;
        int* flag = gcur + NB;
        float* dinv = (float*)(wsi + off_dinv);
        float* y = (float*)(wsi + off_y);
        int* pairs = wsi + off_pairs;
        float* part = (float*)(wsi + off_part);

        k_zero_i<<<(NB + 255) / 256, 256, 0, stream>>>(bcnt, NB);
        k_detect<<<1, 256, 0, stream>>>((const unsigned int*)ei, flag, 8192);
        k_bincount<<<nblkE, 256, 0, stream>>>(ei, flag, E, bcnt, NB);
        k_scanNB<<<1, 1024, 0, stream>>>(bcnt, bbase, gcur, NB);
        k_binfill<<<nblkE, 256, 0, stream>>>(ei, flag, E, gcur, pairs, NB);
        k_deg_dinv<<<NB, 256, 0, stream>>>(pairs, bbase, bcnt, dinv, N);
        k_xw<<<nblkN, 256, 0, stream>>>(x, W, dinv, y, N);
        float qscale = 4.0f / (float)N;
        k_accum<<<NB * 4, 256, 0, stream>>>(pairs, bbase, bcnt, y, part,
                                            qscale);
        int mthreads = N * OUT_CH;
        k_merge<<<(mthreads + 255) / 256, 256, 0, stream>>>(part, y, dinv, b,
                                                            out, N);
    } else {
        // -------- fallback: atomic scatter --------
        int* wsi = (int*)d_ws;
        int* cnt = wsi;                     // N
        int* flag = cnt + N;                // 1
        size_t off = ((size_t)N + 2) & ~(size_t)1;
        float* dinv = (float*)(wsi + off);  // N
        float* y = dinv + N;                // 10N

        k_zero_i<<<nblkN, 256, 0, stream>>>(cnt, N);
        k_detect<<<1, 256, 0, stream>>>((const unsigned int*)ei, flag, 8192);
        k_count_fb<<<4096, 256, 0, stream>>>(ei, cnt, flag, E);
        k_xw_fb<<<nblkN, 256, 0, stream>>>(x, W, cnt, dinv, y, out, N);
        k_scatter_fb<<<4096, 256, 0, stream>>>(ei, y, out, flag, E);
        k_final_fb<<<nblkN, 256, 0, stream>>>(dinv, b, out, N);
    }
}

// Round 6
// 156.514 us; speedup vs baseline: 11.5039x; 1.8590x over previous
//
#include <hip/hip_runtime.h>

#define IN_CH 128
#define OUT_CH 10
#define YPAD 16                    // y row padded to 64 B (one cache line)
#define SHIFT 7                    // nodes per bucket = 128
#define NPB 128
#define CHUNK 8192                 // edges per block in binning kernels
#define CCAP 1024                  // pairs per counting-sort round in k_accum

// ============================================================================
// Shared helpers
// ============================================================================

// Detect whether edge_index arrived as int64 or int32 (odd words all zero
// for int64 values < 2^17). flag=1 -> int32, flag=0 -> int64. Deterministic.
__global__ void k_detect(const unsigned int* __restrict__ w, int* flag,
                         int nwords_check) {
    __shared__ int any_nz;
    if (threadIdx.x == 0) any_nz = 0;
    __syncthreads();
    int local = 0;
    for (int i = threadIdx.x; i < nwords_check; i += blockDim.x)
        if (w[2 * i + 1] != 0u) local = 1;
    if (local) atomicOr(&any_nz, 1);
    __syncthreads();
    if (threadIdx.x == 0) *flag = any_nz;
}

__global__ void k_zero_i(int* __restrict__ p, int n) {
    int i = blockIdx.x * blockDim.x + threadIdx.x;
    int stride = gridDim.x * blockDim.x;
    for (; i < n; i += stride) p[i] = 0;
}

__device__ __forceinline__ int load_dst(const void* ei, bool is32, long long E,
                                        long long i) {
    return is32 ? ((const int*)ei)[E + i] : (int)((const long long*)ei)[E + i];
}
__device__ __forceinline__ int load_src(const void* ei, bool is32, long long E,
                                        long long i) {
    return is32 ? ((const int*)ei)[i] : (int)((const long long*)ei)[i];
}

// ============================================================================
// Bucketed-gather path (primary)
// ============================================================================

// Per-chunk LDS histogram of buckets, flushed with one atomic per bucket.
__global__ void k_bincount(const void* __restrict__ ei,
                           const int* __restrict__ flag, int E,
                           int* __restrict__ bcnt, int NB) {
    __shared__ int h[1024];
    for (int i = threadIdx.x; i < NB; i += blockDim.x) h[i] = 0;
    __syncthreads();
    const bool is32 = (*flag != 0);
    long long base = (long long)blockIdx.x * CHUNK;
    int lim = (int)min((long long)CHUNK, (long long)E - base);
    for (int i = threadIdx.x; i < lim; i += blockDim.x) {
        int d = load_dst(ei, is32, E, base + i);
        atomicAdd(&h[d >> SHIFT], 1);
    }
    __syncthreads();
    for (int i = threadIdx.x; i < NB; i += blockDim.x)
        if (h[i]) atomicAdd(&bcnt[i], h[i]);
}

// Exclusive scan of bcnt[NB] (NB <= 1024) -> bbase, gcursor
__global__ void k_scanNB(const int* __restrict__ bcnt, int* __restrict__ bbase,
                         int* __restrict__ gcur, int NB) {
    __shared__ int s[1024];
    int tid = threadIdx.x;
    int v = (tid < NB) ? bcnt[tid] : 0;
    s[tid] = v;
    __syncthreads();
    for (int off = 1; off < 1024; off <<= 1) {
        int t = (tid >= off) ? s[tid - off] : 0;
        __syncthreads();
        s[tid] += t;
        __syncthreads();
    }
    if (tid < NB) {
        int e = s[tid] - v;
        bbase[tid] = e;
        gcur[tid] = e;
    }
}

// Per chunk: LDS hist -> reserve contiguous per-bucket runs via one global
// atomic per (block,bucket) -> write packed (src<<7 | dst&127) into the runs.
__global__ void k_binfill(const void* __restrict__ ei,
                          const int* __restrict__ flag, int E,
                          int* __restrict__ gcur, int* __restrict__ pairs,
                          int NB) {
    __shared__ int h[1024];
    __shared__ int cur[1024];
    for (int i = threadIdx.x; i < NB; i += blockDim.x) h[i] = 0;
    __syncthreads();
    const bool is32 = (*flag != 0);
    long long base = (long long)blockIdx.x * CHUNK;
    int lim = (int)min((long long)CHUNK, (long long)E - base);
    for (int i = threadIdx.x; i < lim; i += blockDim.x) {
        int d = load_dst(ei, is32, E, base + i);
        atomicAdd(&h[d >> SHIFT], 1);
    }
    __syncthreads();
    for (int i = threadIdx.x; i < NB; i += blockDim.x)
        cur[i] = h[i] ? atomicAdd(&gcur[i], h[i]) : 0;
    __syncthreads();
    for (int i = threadIdx.x; i < lim; i += blockDim.x) {
        int s = load_src(ei, is32, E, base + i);
        int d = load_dst(ei, is32, E, base + i);
        int slot = atomicAdd(&cur[d >> SHIFT], 1);
        pairs[slot] = (int)(((unsigned)s << SHIFT) | (unsigned)(d & (NPB - 1)));
    }
}

// One block per bucket: LDS histogram of its 128-node range -> dinv.
__global__ void k_deg_dinv(const int* __restrict__ pairs,
                           const int* __restrict__ bbase,
                           const int* __restrict__ bcnt,
                           float* __restrict__ dinv, int N) {
    __shared__ int deg[NPB];
    int tid = threadIdx.x;
    if (tid < NPB) deg[tid] = 0;
    __syncthreads();
    int b = blockIdx.x;
    int beg = bbase[b], c = bcnt[b];
    for (int i = tid; i < c; i += blockDim.x)
        atomicAdd(&deg[pairs[beg + i] & (NPB - 1)], 1);
    __syncthreads();
    if (tid < NPB) {
        int n = b * NPB + tid;
        if (n < N) dinv[n] = rsqrtf(1.0f + (float)deg[tid]);
    }
}

// y[n] = dinv[n] * (x[n] @ W), row padded to YPAD floats (64 B aligned)
__global__ void k_xw(const float* __restrict__ x, const float* __restrict__ W,
                     const float* __restrict__ dinv, float* __restrict__ y,
                     int N) {
    __shared__ float Wt[OUT_CH][IN_CH];
    for (int i = threadIdx.x; i < IN_CH * OUT_CH; i += blockDim.x) {
        int k = i / OUT_CH, c = i - k * OUT_CH;
        Wt[c][k] = W[i];
    }
    __syncthreads();

    int n = blockIdx.x * blockDim.x + threadIdx.x;
    if (n >= N) return;

    float acc[OUT_CH];
#pragma unroll
    for (int c = 0; c < OUT_CH; ++c) acc[c] = 0.0f;

    const float4* xr = (const float4*)(x + (size_t)n * IN_CH);
#pragma unroll 4
    for (int k4 = 0; k4 < IN_CH / 4; ++k4) {
        float4 xv = xr[k4];
#pragma unroll
        for (int c = 0; c < OUT_CH; ++c) {
            float4 wv = *(const float4*)&Wt[c][k4 * 4];
            acc[c] += xv.x * wv.x + xv.y * wv.y + xv.z * wv.z + xv.w * wv.w;
        }
    }

    float d = dinv[n];
    float4* yr = (float4*)(y + (size_t)n * YPAD);
    float4 o0, o1;
    o0.x = d * acc[0]; o0.y = d * acc[1]; o0.z = d * acc[2]; o0.w = d * acc[3];
    o1.x = d * acc[4]; o1.y = d * acc[5]; o1.z = d * acc[6]; o1.w = d * acc[7];
    yr[0] = o0;
    yr[1] = o1;
    float2 o2;
    o2.x = d * acc[8]; o2.y = d * acc[9];
    ((float2*)yr)[4] = o2;
}

// 4 blocks per bucket, block (b,s) owns slice s of bucket b's packed pairs.
// Per <=1024-pair round: counting-sort the pairs by dst row in LDS (int
// atomics only -- native ds ops), then thread t = (row<<1)|half privately
// accumulates its contiguous run of y[src] gathers in VGPRs. Halves combine
// via shfl; partial flushed coalesced. ZERO float LDS/global atomics.
__global__ void k_accum(const int* __restrict__ pairs,
                        const int* __restrict__ bbase,
                        const int* __restrict__ bcnt,
                        const float* __restrict__ y,
                        float* __restrict__ part) {
    __shared__ unsigned sorted[CCAP];
    __shared__ int hist[NPB];
    __shared__ int base[NPB];
    __shared__ int cur[NPB];

    int tid = threadIdx.x;
    int b = blockIdx.x >> 2;
    int s = blockIdx.x & 3;
    int beg = bbase[b];
    int c = bcnt[b];
    int lo = beg + (int)(((long long)c * s) >> 2);
    int hi = beg + (int)(((long long)c * (s + 1)) >> 2);

    int myrow = tid >> 1;
    int h = tid & 1;

    float acc[OUT_CH];
#pragma unroll
    for (int k = 0; k < OUT_CH; ++k) acc[k] = 0.0f;

    for (int clo = lo; clo < hi; clo += CCAP) {
        int m = min(CCAP, hi - clo);

        if (tid < NPB) hist[tid] = 0;
        __syncthreads();

        // read my <=4 pairs, build histogram (native int LDS atomics)
        unsigned mine[4];
        int nm = 0;
        for (int i = tid; i < m; i += 256) {
            unsigned pp = (unsigned)pairs[clo + i];
            mine[nm++] = pp;
            atomicAdd(&hist[pp & (NPB - 1)], 1);
        }
        __syncthreads();

        // exclusive scan of hist[128] (Hillis-Steele; all threads barrier)
        if (tid < NPB) base[tid] = hist[tid];
        __syncthreads();
        for (int off = 1; off < NPB; off <<= 1) {
            int t = 0;
            if (tid < NPB && tid >= off) t = base[tid - off];
            __syncthreads();
            if (tid < NPB) base[tid] += t;
            __syncthreads();
        }
        if (tid < NPB) {
            int e = base[tid] - hist[tid];
            base[tid] = e;
            cur[tid] = e;
        }
        __syncthreads();

        // scatter src ids into row-sorted order
        for (int j = 0; j < nm; ++j) {
            unsigned pp = mine[j];
            int slot = atomicAdd(&cur[pp & (NPB - 1)], 1);
            sorted[slot] = pp >> SHIFT;
        }
        __syncthreads();

        // private VGPR accumulation over my row's run (2 threads/row)
        int rb = base[myrow];
        int rl = hist[myrow];
        for (int j = h; j < rl; j += 2) {
            unsigned src = sorted[rb + j];
            const float4* yr = (const float4*)(y + (size_t)src * YPAD);
            float4 v0 = yr[0];
            float4 v1 = yr[1];
            float2 v2 = ((const float2*)yr)[4];
            acc[0] += v0.x; acc[1] += v0.y; acc[2] += v0.z; acc[3] += v0.w;
            acc[4] += v1.x; acc[5] += v1.y; acc[6] += v1.z; acc[7] += v1.w;
            acc[8] += v2.x; acc[9] += v2.y;
        }
        __syncthreads();  // protect hist/sorted before next round
    }

    // combine the two halves of each row (adjacent lanes)
#pragma unroll
    for (int k = 0; k < OUT_CH; ++k) acc[k] += __shfl_xor(acc[k], 1);

    if (h == 0) {
        float* dst = part + (size_t)blockIdx.x * (NPB * OUT_CH) +
                     (size_t)myrow * OUT_CH;
#pragma unroll
        for (int k = 0; k < OUT_CH; ++k) dst[k] = acc[k];
    }
}

// out[n][ch] = dinv[n] * (sum of 4 slice partials + y[n][ch]) + bias[ch]
__global__ void k_merge(const float* __restrict__ part,
                        const float* __restrict__ y,
                        const float* __restrict__ dinv,
                        const float* __restrict__ bias,
                        float* __restrict__ out, int N) {
    int idx = blockIdx.x * blockDim.x + threadIdx.x;
    if (idx >= N * OUT_CH) return;
    int n = idx / OUT_CH;
    int ch = idx - n * OUT_CH;
    int b = n >> SHIFT;
    int local = (n & (NPB - 1)) * OUT_CH + ch;
    size_t base_slot = (size_t)(b << 2);
    float s = part[(base_slot + 0) * (NPB * OUT_CH) + local] +
              part[(base_slot + 1) * (NPB * OUT_CH) + local] +
              part[(base_slot + 2) * (NPB * OUT_CH) + local] +
              part[(base_slot + 3) * (NPB * OUT_CH) + local];
    out[idx] = dinv[n] * (s + y[(size_t)n * YPAD + ch]) + bias[ch];
}

// ============================================================================
// Fallback path (atomic scatter) — used only if ws too small / N too large
// ============================================================================

__global__ void k_count_fb(const void* __restrict__ ei, int* __restrict__ cnt,
                           const int* __restrict__ flag, int E) {
    const bool is32 = (*flag != 0);
    long long i = (long long)blockIdx.x * blockDim.x + threadIdx.x;
    long long stride = (long long)gridDim.x * blockDim.x;
    for (; i < E; i += stride) atomicAdd(&cnt[load_dst(ei, is32, E, i)], 1);
}

__global__ void k_xw_fb(const float* __restrict__ x,
                        const float* __restrict__ W,
                        const int* __restrict__ cnt, float* __restrict__ dinv,
                        float* __restrict__ y, float* __restrict__ out_seed,
                        int N) {
    __shared__ float Wt[OUT_CH][IN_CH];
    for (int i = threadIdx.x; i < IN_CH * OUT_CH; i += blockDim.x) {
        int k = i / OUT_CH, c = i - k * OUT_CH;
        Wt[c][k] = W[i];
    }
    __syncthreads();
    int n = blockIdx.x * blockDim.x + threadIdx.x;
    if (n >= N) return;
    float acc[OUT_CH];
#pragma unroll
    for (int c = 0; c < OUT_CH; ++c) acc[c] = 0.0f;
    const float4* xr = (const float4*)(x + (size_t)n * IN_CH);
#pragma unroll 4
    for (int k4 = 0; k4 < IN_CH / 4; ++k4) {
        float4 xv = xr[k4];
#pragma unroll
        for (int c = 0; c < OUT_CH; ++c) {
            float4 wv = *(const float4*)&Wt[c][k4 * 4];
            acc[c] += xv.x * wv.x + xv.y * wv.y + xv.z * wv.z + xv.w * wv.w;
        }
    }
    float d = rsqrtf(1.0f + (float)cnt[n]);
    dinv[n] = d;
    float2* yr = (float2*)(y + (size_t)n * OUT_CH);
    float2* orow = (float2*)(out_seed + (size_t)n * OUT_CH);
#pragma unroll
    for (int c2 = 0; c2 < OUT_CH / 2; ++c2) {
        float2 v;
        v.x = d * acc[2 * c2];
        v.y = d * acc[2 * c2 + 1];
        yr[c2] = v;
        orow[c2] = v;
    }
}

__global__ void k_scatter_fb(const void* __restrict__ ei,
                             const float* __restrict__ y,
                             float* __restrict__ out,
                             const int* __restrict__ flag, int E) {
    const bool is32 = (*flag != 0);
    long long i = (long long)blockIdx.x * blockDim.x + threadIdx.x;
    long long stride = (long long)gridDim.x * blockDim.x;
    for (; i < E; i += stride) {
        long long s = load_src(ei, is32, E, i);
        long long t = load_dst(ei, is32, E, i);
        const float2* yr = (const float2*)(y + s * OUT_CH);
        float2 v0 = yr[0], v1 = yr[1], v2 = yr[2], v3 = yr[3], v4 = yr[4];
        float* orow = out + t * OUT_CH;
        atomicAdd(&orow[0], v0.x);
        atomicAdd(&orow[1], v0.y);
        atomicAdd(&orow[2], v1.x);
        atomicAdd(&orow[3], v1.y);
        atomicAdd(&orow[4], v2.x);
        atomicAdd(&orow[5], v2.y);
        atomicAdd(&orow[6], v3.x);
        atomicAdd(&orow[7], v3.y);
        atomicAdd(&orow[8], v4.x);
        atomicAdd(&orow[9], v4.y);
    }
}

__global__ void k_final_fb(const float* __restrict__ dinv,
                           const float* __restrict__ b,
                           float* __restrict__ out, int N) {
    int n = blockIdx.x * blockDim.x + threadIdx.x;
    if (n >= N) return;
    float d = dinv[n];
    float2* orow = (float2*)(out + (size_t)n * OUT_CH);
#pragma unroll
    for (int c2 = 0; c2 < OUT_CH / 2; ++c2) {
        float2 v = orow[c2];
        v.x = v.x * d + b[2 * c2];
        v.y = v.y * d + b[2 * c2 + 1];
        orow[c2] = v;
    }
}

// ============================================================================
// Launch
// ============================================================================

extern "C" void kernel_launch(void* const* d_in, const int* in_sizes, int n_in,
                              void* d_out, int out_size, void* d_ws,
                              size_t ws_size, hipStream_t stream) {
    const float* x = (const float*)d_in[0];
    const void* ei = d_in[1];
    const float* W = (const float*)d_in[2];
    const float* b = (const float*)d_in[3];
    float* out = (float*)d_out;

    int N = in_sizes[0] / IN_CH;  // 100000
    int E = in_sizes[1] / 2;      // 3200000

    int NB = (N + NPB - 1) / NPB;  // buckets (782)
    int nblkN = (N + 255) / 256;
    int nblkE = (E + CHUNK - 1) / CHUNK;

    // primary ws layout (4B units):
    //   bcnt[NB] | bbase[NB] | gcur[NB] | flag | pad16 | dinv[N] | pad16 |
    //   y[YPAD*N] (64B-aligned rows) | pairs[E] | pad16 | part[NB*4*1280]
    size_t off_dinv = (((size_t)3 * NB + 1) + 15) & ~(size_t)15;
    size_t off_y = ((off_dinv + (size_t)N) + 15) & ~(size_t)15;
    size_t off_pairs = off_y + (size_t)YPAD * N;
    size_t off_part = ((off_pairs + (size_t)E) + 15) & ~(size_t)15;
    size_t needed = (off_part + ((size_t)NB * 4) * (NPB * OUT_CH)) * 4;

    if (ws_size >= needed && NB <= 1024 && N <= (1 << 24)) {
        int* wsi = (int*)d_ws;
        int* bcnt = wsi;
        int* bbase = bcnt + NB;
        int* gcur = bbase + NB;
        int* flag = gcur + NB;
        float* dinv = (float*)(wsi + off_dinv);
        float* y = (float*)(wsi + off_y);
        int* pairs = wsi + off_pairs;
        float* part = (float*)(wsi + off_part);

        k_zero_i<<<(NB + 255) / 256, 256, 0, stream>>>(bcnt, NB);
        k_detect<<<1, 256, 0, stream>>>((const unsigned int*)ei, flag, 8192);
        k_bincount<<<nblkE, 256, 0, stream>>>(ei, flag, E, bcnt, NB);
        k_scanNB<<<1, 1024, 0, stream>>>(bcnt, bbase, gcur, NB);
        k_binfill<<<nblkE, 256, 0, stream>>>(ei, flag, E, gcur, pairs, NB);
        k_deg_dinv<<<NB, 256, 0, stream>>>(pairs, bbase, bcnt, dinv, N);
        k_xw<<<nblkN, 256, 0, stream>>>(x, W, dinv, y, N);
        k_accum<<<NB * 4, 256, 0, stream>>>(pairs, bbase, bcnt, y, part);
        int mthreads = N * OUT_CH;
        k_merge<<<(mthreads + 255) / 256, 256, 0, stream>>>(part, y, dinv, b,
                                                            out, N);
    } else {
        // -------- fallback: atomic scatter --------
        int* wsi = (int*)d_ws;
        int* cnt = wsi;                     // N
        int* flag = cnt + N;                // 1
        size_t off = ((size_t)N + 2) & ~(size_t)1;
        float* dinv = (float*)(wsi + off);  // N
        float* y = dinv + N;                // 10N

        k_zero_i<<<nblkN, 256, 0, stream>>>(cnt, N);
        k_detect<<<1, 256, 0, stream>>>((const unsigned int*)ei, flag, 8192);
        k_count_fb<<<4096, 256, 0, stream>>>(ei, cnt, flag, E);
        k_xw_fb<<<nblkN, 256, 0, stream>>>(x, W, cnt, dinv, y, out, N);
        k_scatter_fb<<<4096, 256, 0, stream>>>(ei, y, out, flag, E);
        k_final_fb<<<nblkN, 256, 0, stream>>>(dinv, b, out, N);
    }
}